// Round 3
// baseline (523.792 us; speedup 1.0000x reference)
//
#include <hip/hip_runtime.h>

#define LL 2048
#define DD 128
#define NB 32
#define KC 64
#define QB 128
#define NCH (LL / KC)
#define SCALE 0.08838834764831845f

typedef short short8 __attribute__((ext_vector_type(8)));
typedef short short4v __attribute__((ext_vector_type(4)));
typedef float f32x4 __attribute__((ext_vector_type(4)));

__device__ __forceinline__ unsigned short f2bf(float f) {
  unsigned int u = __float_as_uint(f);
  u += 0x7fffu + ((u >> 16) & 1u);   // RNE
  return (unsigned short)(u >> 16);
}
__device__ __forceinline__ float bf2f(unsigned short s) {
  return __uint_as_float(((unsigned int)s) << 16);
}

__global__ __launch_bounds__(512, 2) void attn_fused(
    const float* __restrict__ q, const float* __restrict__ k,
    const float* __restrict__ v, float* __restrict__ out) {
  // double-buffered, XOR-swizzled K and V^T tiles + per-wave P staging = 80 KB
  __shared__ __align__(16) unsigned short kT[2][KC * DD];
  __shared__ __align__(16) unsigned short vT[2][DD * KC];
  __shared__ __align__(16) unsigned short pb[8][16 * KC];

  const int tid = threadIdx.x;
  const int w = tid >> 6, l = tid & 63, lg = l >> 4, lr = l & 15;

  // XCD-aware remap: all 16 q-blocks of one batch live on one XCD (i%8).
  const int i0 = blockIdx.x;
  const int b  = (i0 & 7) + 8 * (i0 >> 7);
  const int qx = (i0 >> 3) & 15;
  const int qw = qx * QB + w * 16;

  const float* qb_ = q + (size_t)b * LL * DD;
  const float* kb_ = k + (size_t)b * LL * DD;
  const float* vb_ = v + (size_t)b * LL * DD;
  float* ctx  = out + ((size_t)b * LL + qw) * DD;
  float* attn = out + (size_t)NB * LL * DD + ((size_t)b * LL + qw) * (size_t)LL;

  // staging index maps
  const int kr  = tid >> 5, kc4 = tid & 31;             // K: rows kr+16i, col group kc4
  const unsigned kswz = (kr & 7) << 3;
  const int vr0 = (tid & 15) * 4, vc0 = (tid >> 4) * 4; // V: 4 keys x 4 d per thread

  // ---- Q fragments: lane holds Q[qw+lr][dt*32 + lg*8 + j] ----
  short8 aq[4];
  {
    const float* qrow = qb_ + (size_t)(qw + lr) * DD + lg * 8;
#pragma unroll
    for (int dt = 0; dt < 4; ++dt) {
      f32x4 x0 = *(const f32x4*)(qrow + dt * 32);
      f32x4 x1 = *(const f32x4*)(qrow + dt * 32 + 4);
      short8 a;
#pragma unroll
      for (int j = 0; j < 4; ++j) { a[j] = (short)f2bf(x0[j]); a[4 + j] = (short)f2bf(x1[j]); }
      aq[dt] = a;
    }
  }

  f32x4 pk[4], pv[4];
  float lsum[4] = {0.f, 0.f, 0.f, 0.f};

  // =================== pass 1: softmax denominators ===================
#pragma unroll
  for (int j = 0; j < 4; ++j)
    pk[j] = *(const f32x4*)(kb_ + (size_t)(kr + j * 16) * DD + kc4 * 4);
#pragma unroll
  for (int j = 0; j < 4; ++j) {
    short4v y;
#pragma unroll
    for (int t = 0; t < 4; ++t) y[t] = (short)f2bf(pk[j][t]);
    *(short4v*)&kT[0][((kr + j * 16) * 128 + kc4 * 4) ^ kswz] = y;
  }
  __syncthreads();

  int cur = 0;
  for (int kc = 0; kc < NCH; ++kc) {
    if (kc + 1 < NCH) {
#pragma unroll
      for (int j = 0; j < 4; ++j)
        pk[j] = *(const f32x4*)(kb_ + (size_t)((kc + 1) * KC + kr + j * 16) * DD + kc4 * 4);
    }
    __builtin_amdgcn_s_setprio(1);
#pragma unroll
    for (int kt = 0; kt < 4; ++kt) {
      f32x4 acc = {0.f, 0.f, 0.f, 0.f};
      const int row = kt * 16 + lr;
      const unsigned sw = (row & 7) << 3;
#pragma unroll
      for (int dt = 0; dt < 4; ++dt) {
        short8 bk = *(const short8*)&kT[cur][(row * 128 + dt * 32 + lg * 8) ^ sw];
        acc = __builtin_amdgcn_mfma_f32_16x16x32_bf16(aq[dt], bk, acc, 0, 0, 0);
      }
#pragma unroll
      for (int r = 0; r < 4; ++r) lsum[r] += __expf(acc[r] * SCALE);
    }
    __builtin_amdgcn_s_setprio(0);
    if (kc + 1 < NCH) {
#pragma unroll
      for (int j = 0; j < 4; ++j) {
        short4v y;
#pragma unroll
        for (int t = 0; t < 4; ++t) y[t] = (short)f2bf(pk[j][t]);
        *(short4v*)&kT[cur ^ 1][((kr + j * 16) * 128 + kc4 * 4) ^ kswz] = y;
      }
    }
    __syncthreads();
    cur ^= 1;
  }
#pragma unroll
  for (int r = 0; r < 4; ++r) {
    float s = lsum[r];
    s += __shfl_xor(s, 1); s += __shfl_xor(s, 2);
    s += __shfl_xor(s, 4); s += __shfl_xor(s, 8);
    lsum[r] = 1.0f / s;
  }

  // =================== pass 2: attn write + PV ===================
  f32x4 apv[8];
#pragma unroll
  for (int dt = 0; dt < 8; ++dt) apv[dt] = (f32x4){0.f, 0.f, 0.f, 0.f};

#pragma unroll
  for (int j = 0; j < 4; ++j) {
    pk[j] = *(const f32x4*)(kb_ + (size_t)(kr + j * 16) * DD + kc4 * 4);
    pv[j] = *(const f32x4*)(vb_ + (size_t)(vr0 + j) * DD + vc0);
  }
#pragma unroll
  for (int j = 0; j < 4; ++j) {
    short4v y;
#pragma unroll
    for (int t = 0; t < 4; ++t) y[t] = (short)f2bf(pk[j][t]);
    *(short4v*)&kT[0][((kr + j * 16) * 128 + kc4 * 4) ^ kswz] = y;
  }
#pragma unroll
  for (int j = 0; j < 4; ++j) {
    const int dr = vc0 + j;
    short4v y = {(short)f2bf(pv[0][j]), (short)f2bf(pv[1][j]),
                 (short)f2bf(pv[2][j]), (short)f2bf(pv[3][j])};
    *(short4v*)&vT[0][dr * KC + (vr0 ^ ((dr & 7) << 3))] = y;
  }
  __syncthreads();

  cur = 0;
  for (int kc = 0; kc < NCH; ++kc) {
    if (kc + 1 < NCH) {
#pragma unroll
      for (int j = 0; j < 4; ++j) {
        pk[j] = *(const f32x4*)(kb_ + (size_t)((kc + 1) * KC + kr + j * 16) * DD + kc4 * 4);
        pv[j] = *(const f32x4*)(vb_ + (size_t)((kc + 1) * KC + vr0 + j) * DD + vc0);
      }
    }

    // ---- QK^T + exp + stash P (bf16) in per-wave LDS ----
    __builtin_amdgcn_s_setprio(1);
#pragma unroll
    for (int kt = 0; kt < 4; ++kt) {
      f32x4 acc = {0.f, 0.f, 0.f, 0.f};
      const int row = kt * 16 + lr;
      const unsigned sw = (row & 7) << 3;
#pragma unroll
      for (int dt = 0; dt < 4; ++dt) {
        short8 bk = *(const short8*)&kT[cur][(row * 128 + dt * 32 + lg * 8) ^ sw];
        acc = __builtin_amdgcn_mfma_f32_16x16x32_bf16(aq[dt], bk, acc, 0, 0, 0);
      }
#pragma unroll
      for (int r = 0; r < 4; ++r) {
        float p = __expf(acc[r] * SCALE) * lsum[r];
        const int qr = lg * 4 + r;
        pb[w][qr * KC + ((kt * 16 + lr) ^ ((qr & 7) << 3))] = f2bf(p);
      }
    }
    __builtin_amdgcn_s_setprio(0);

    // ---- PV A-fragments (wave-internal LDS, no barrier needed) ----
    short8 ap0 = *(const short8*)&pb[w][lr * KC + ((lg * 8) ^ ((lr & 7) << 3))];
    short8 ap1 = *(const short8*)&pb[w][lr * KC + ((32 + lg * 8) ^ ((lr & 7) << 3))];

    // ---- coalesced nontemporal attn store: 16 bf16/lane -> 4 dwordx4 ----
    {
      const int row = l >> 2, cb = (l & 3) * 16;
      const unsigned sw = (row & 7) << 3;
      short8 s0 = *(const short8*)&pb[w][row * KC + (cb ^ sw)];
      short8 s1 = *(const short8*)&pb[w][row * KC + ((cb + 8) ^ sw)];
      float* dst = attn + (size_t)row * LL + kc * KC + cb;
      f32x4 o0, o1, o2, o3;
#pragma unroll
      for (int j = 0; j < 4; ++j) {
        o0[j] = bf2f((unsigned short)s0[j]);
        o1[j] = bf2f((unsigned short)s0[4 + j]);
        o2[j] = bf2f((unsigned short)s1[j]);
        o3[j] = bf2f((unsigned short)s1[4 + j]);
      }
      __builtin_nontemporal_store(o0, (f32x4*)(dst));
      __builtin_nontemporal_store(o1, (f32x4*)(dst + 4));
      __builtin_nontemporal_store(o2, (f32x4*)(dst + 8));
      __builtin_nontemporal_store(o3, (f32x4*)(dst + 12));
    }

    // ---- PV ----
    __builtin_amdgcn_s_setprio(1);
#pragma unroll
    for (int dt = 0; dt < 8; ++dt) {
      const int vrow = dt * 16 + lr;
      const unsigned sw = (vrow & 7) << 3;
      short8 b0 = *(const short8*)&vT[cur][vrow * KC + ((lg * 8) ^ sw)];
      short8 b1 = *(const short8*)&vT[cur][vrow * KC + ((32 + lg * 8) ^ sw)];
      apv[dt] = __builtin_amdgcn_mfma_f32_16x16x32_bf16(ap0, b0, apv[dt], 0, 0, 0);
      apv[dt] = __builtin_amdgcn_mfma_f32_16x16x32_bf16(ap1, b1, apv[dt], 0, 0, 0);
    }
    __builtin_amdgcn_s_setprio(0);

    // ---- stage next chunk into the other buffer ----
    if (kc + 1 < NCH) {
#pragma unroll
      for (int j = 0; j < 4; ++j) {
        short4v y;
#pragma unroll
        for (int t = 0; t < 4; ++t) y[t] = (short)f2bf(pk[j][t]);
        *(short4v*)&kT[cur ^ 1][((kr + j * 16) * 128 + kc4 * 4) ^ kswz] = y;
      }
#pragma unroll
      for (int j = 0; j < 4; ++j) {
        const int dr = vc0 + j;
        short4v y = {(short)f2bf(pv[0][j]), (short)f2bf(pv[1][j]),
                     (short)f2bf(pv[2][j]), (short)f2bf(pv[3][j])};
        *(short4v*)&vT[cur ^ 1][dr * KC + (vr0 ^ ((dr & 7) << 3))] = y;
      }
    }
    __syncthreads();
    cur ^= 1;
  }

  // ---- context store ----
#pragma unroll
  for (int dt = 0; dt < 8; ++dt)
#pragma unroll
    for (int r = 0; r < 4; ++r)
      __builtin_nontemporal_store(apv[dt][r], ctx + (size_t)(lg * 4 + r) * DD + dt * 16 + lr);
}

extern "C" void kernel_launch(void* const* d_in, const int* in_sizes, int n_in,
                              void* d_out, int out_size, void* d_ws, size_t ws_size,
                              hipStream_t stream) {
  const float* q = (const float*)d_in[0];
  const float* k = (const float*)d_in[1];
  const float* v = (const float*)d_in[2];
  float* out = (float*)d_out;
  dim3 grid((LL / QB) * NB);
  dim3 block(512);
  attn_fused<<<grid, block, 0, stream>>>(q, k, v, out);
}

// Round 4
// 288.250 us; speedup vs baseline: 1.8171x; 1.8171x over previous
//
#include <hip/hip_runtime.h>
#include <hip/hip_bf16.h>

#define LL 2048
#define DD 128
#define NB 32
#define KC 64
#define QB 128
#define NCH (LL / KC)
#define SCALE 0.08838834764831845f

typedef short short8 __attribute__((ext_vector_type(8)));
typedef float f32x4 __attribute__((ext_vector_type(4)));
typedef float f32x16 __attribute__((ext_vector_type(16)));
typedef int int4v __attribute__((ext_vector_type(4)));
typedef unsigned int uint2v __attribute__((ext_vector_type(2)));

__device__ __forceinline__ unsigned int pkbf(float lo, float hi) {
  __hip_bfloat162 h = __float22bfloat162_rn(make_float2(lo, hi));
  union { __hip_bfloat162 h2; unsigned int u; } c;
  c.h2 = h;
  return c.u;
}
__device__ __forceinline__ float asf(unsigned int u) { return __uint_as_float(u); }

__global__ __launch_bounds__(256, 2) void attn_fused(
    const float* __restrict__ q, const float* __restrict__ k,
    const float* __restrict__ v, float* __restrict__ out) {
  // double-buffered, XOR-swizzled K [key][d] and V^T [d][key] tiles: 64 KB total
  __shared__ __align__(16) unsigned short kT[2][KC * DD];
  __shared__ __align__(16) unsigned short vT[2][DD * KC];

  const int tid = threadIdx.x;
  const int w = tid >> 6, l = tid & 63;
  const int qi = l & 31;          // lane's q-row (within wave's 32)
  const int hi = l >> 5;          // half select
  const unsigned swz = (l & 7) << 3;

  // XCD-aware remap: 16 q-blocks of one batch share an XCD
  const int i0 = blockIdx.x;
  const int b  = (i0 & 7) + 8 * (i0 >> 7);
  const int qx = (i0 >> 3) & 15;
  const int qw = qx * QB + w * 32;

  const float* qb_ = q + (size_t)b * LL * DD;
  const float* kb_ = k + (size_t)b * LL * DD;
  const float* vb_ = v + (size_t)b * LL * DD;
  float* ctxW = out + ((size_t)b * LL + qw) * DD;
  float* attnRow = out + (size_t)NB * LL * DD + ((size_t)b * LL + qw + qi) * (size_t)LL;

  // staging maps
  const int krow = (tid >> 5) & 7, kc4 = tid & 31;   // K: rows krow+8j, f32x4 col kc4
  const int vkey0 = (tid & 15) * 4, vd0 = (tid >> 4) * 8; // V: 4 keys x 8 d

  // ---- Q fragments (B operand): lane holds Q[qw+qi][dt*16 + hi*8 + j] ----
  short8 aq[8];
  {
    const float* qrow = qb_ + (size_t)(qw + qi) * DD + hi * 8;
#pragma unroll
    for (int dt = 0; dt < 8; ++dt) {
      f32x4 x0 = *(const f32x4*)(qrow + dt * 16);
      f32x4 x1 = *(const f32x4*)(qrow + dt * 16 + 4);
      uint2v u0 = {pkbf(x0[0], x0[1]), pkbf(x0[2], x0[3])};
      uint2v u1 = {pkbf(x1[0], x1[1]), pkbf(x1[2], x1[3])};
      int4v pw = {(int)u0[0], (int)u0[1], (int)u1[0], (int)u1[1]};
      aq[dt] = __builtin_bit_cast(short8, pw);
    }
  }

  f32x4 pk[8], pv[8];

  auto loadK = [&](int kc) {
#pragma unroll
    for (int j = 0; j < 8; ++j)
      pk[j] = *(const f32x4*)(kb_ + (size_t)(kc * KC + krow + 8 * j) * DD + kc4 * 4);
  };
  auto writeK = [&](int buf) {
#pragma unroll
    for (int j = 0; j < 8; ++j) {
      uint2v y = {pkbf(pk[j][0], pk[j][1]), pkbf(pk[j][2], pk[j][3])};
      *(uint2v*)&kT[buf][(krow + 8 * j) * DD + ((kc4 * 4) ^ (krow << 3))] = y;
    }
  };
  auto loadV = [&](int kc) {
#pragma unroll
    for (int i = 0; i < 4; ++i)
#pragma unroll
      for (int h = 0; h < 2; ++h)
        pv[i * 2 + h] = *(const f32x4*)(vb_ + (size_t)(kc * KC + vkey0 + i) * DD + vd0 + h * 4);
  };
  auto writeV = [&](int buf) {
#pragma unroll
    for (int dd = 0; dd < 8; ++dd) {
      const int h = dd >> 2, c = dd & 3;
      uint2v y = {pkbf(pv[0 + h][c], pv[2 + h][c]),
                  pkbf(pv[4 + h][c], pv[6 + h][c])};
      *(uint2v*)&vT[buf][(vd0 + dd) * KC + (vkey0 ^ (dd << 3))] = y;
    }
  };

  // =================== pass 1: softmax denominators ===================
  float s = 0.f;
  loadK(0); writeK(0);
  __syncthreads();
  int cur = 0;
  for (int kc = 0; kc < NCH; ++kc) {
    if (kc + 1 < NCH) loadK(kc + 1);
#pragma unroll
    for (int t = 0; t < 2; ++t) {
      f32x16 acc = {0.f,0.f,0.f,0.f,0.f,0.f,0.f,0.f,0.f,0.f,0.f,0.f,0.f,0.f,0.f,0.f};
      const int arow = (t * 32 + qi) * DD;
      __builtin_amdgcn_s_setprio(1);
#pragma unroll
      for (int dt = 0; dt < 8; ++dt) {
        short8 ka = *(const short8*)&kT[cur][arow + ((dt * 16 + hi * 8) ^ swz)];
        acc = __builtin_amdgcn_mfma_f32_32x32x16_bf16(ka, aq[dt], acc, 0, 0, 0);
      }
      __builtin_amdgcn_s_setprio(0);
#pragma unroll
      for (int r = 0; r < 16; ++r) s += __expf(acc[r] * SCALE);
    }
    if (kc + 1 < NCH) writeK(cur ^ 1);
    __syncthreads();
    cur ^= 1;
  }
  s += __shfl_xor(s, 32);
  const float rs = 1.0f / s;

  // =================== pass 2: attn + PV ===================
  f32x16 apv[4];
#pragma unroll
  for (int nt = 0; nt < 4; ++nt)
    apv[nt] = (f32x16){0.f,0.f,0.f,0.f,0.f,0.f,0.f,0.f,0.f,0.f,0.f,0.f,0.f,0.f,0.f,0.f};

  loadK(0); loadV(0); writeK(0); writeV(0);
  __syncthreads();
  cur = 0;
  for (int kc = 0; kc < NCH; ++kc) {
    if (kc + 1 < NCH) { loadK(kc + 1); loadV(kc + 1); }

#pragma unroll
    for (int t = 0; t < 2; ++t) {
      f32x16 acc = {0.f,0.f,0.f,0.f,0.f,0.f,0.f,0.f,0.f,0.f,0.f,0.f,0.f,0.f,0.f,0.f};
      const int arow = (t * 32 + qi) * DD;
      __builtin_amdgcn_s_setprio(1);
#pragma unroll
      for (int dt = 0; dt < 8; ++dt) {
        short8 ka = *(const short8*)&kT[cur][arow + ((dt * 16 + hi * 8) ^ swz)];
        acc = __builtin_amdgcn_mfma_f32_32x32x16_bf16(ka, aq[dt], acc, 0, 0, 0);
      }
      __builtin_amdgcn_s_setprio(0);

      float p[16];
#pragma unroll
      for (int r = 0; r < 16; ++r) p[r] = __expf(acc[r] * SCALE) * rs;

#pragma unroll
      for (int kt2 = 0; kt2 < 2; ++kt2) {
        // pack to bf16 pairs; build PV A-frag words via half-swap
        const int pb0 = kt2 * 8;
        unsigned a0 = pkbf(p[pb0 + 0], p[pb0 + 1]);
        unsigned a1 = pkbf(p[pb0 + 2], p[pb0 + 3]);
        unsigned b0 = pkbf(p[pb0 + 4], p[pb0 + 5]);
        unsigned b1 = pkbf(p[pb0 + 6], p[pb0 + 7]);
        unsigned a0s = (unsigned)__shfl_xor((int)a0, 32);
        unsigned a1s = (unsigned)__shfl_xor((int)a1, 32);
        unsigned b0s = (unsigned)__shfl_xor((int)b0, 32);
        unsigned b1s = (unsigned)__shfl_xor((int)b1, 32);
        // w_j holds keys (tile-local) hi*8 + {2j, 2j+1}
        unsigned w0 = hi ? b0s : a0;
        unsigned w1 = hi ? b1s : a1;
        unsigned w2 = hi ? b0 : a0s;
        unsigned w3 = hi ? b1 : a1s;
        int4v pw = {(int)w0, (int)w1, (int)w2, (int)w3};
        short8 pa = __builtin_bit_cast(short8, pw);

        // attn store: lane's row qi, 8 consecutive keys
        {
          f32x4 s0 = {asf(w0 << 16), asf(w0 & 0xffff0000u),
                      asf(w1 << 16), asf(w1 & 0xffff0000u)};
          f32x4 s1 = {asf(w2 << 16), asf(w2 & 0xffff0000u),
                      asf(w3 << 16), asf(w3 & 0xffff0000u)};
          float* dst = attnRow + kc * KC + t * 32 + kt2 * 16 + hi * 8;
          *(f32x4*)dst = s0;
          *(f32x4*)(dst + 4) = s1;
        }

        // PV: apv[nt] += pa x V
        const int vcol = (t * 32 + kt2 * 16 + hi * 8) ^ swz;
        __builtin_amdgcn_s_setprio(1);
#pragma unroll
        for (int nt = 0; nt < 4; ++nt) {
          short8 bv = *(const short8*)&vT[cur][(nt * 32 + qi) * KC + vcol];
          apv[nt] = __builtin_amdgcn_mfma_f32_32x32x16_bf16(pa, bv, apv[nt], 0, 0, 0);
        }
        __builtin_amdgcn_s_setprio(0);
      }
    }

    if (kc + 1 < NCH) { writeK(cur ^ 1); writeV(cur ^ 1); }
    __syncthreads();
    cur ^= 1;
  }

  // ---- context store: D rows = (r&3)+8*(r>>2)+4*hi, col = nt*32+qi ----
#pragma unroll
  for (int nt = 0; nt < 4; ++nt)
#pragma unroll
    for (int r = 0; r < 16; ++r) {
      const int row = (r & 3) + 8 * (r >> 2) + 4 * hi;
      ctxW[(size_t)row * DD + nt * 32 + qi] = apv[nt][r];
    }
}

extern "C" void kernel_launch(void* const* d_in, const int* in_sizes, int n_in,
                              void* d_out, int out_size, void* d_ws, size_t ws_size,
                              hipStream_t stream) {
  const float* q = (const float*)d_in[0];
  const float* k = (const float*)d_in[1];
  const float* v = (const float*)d_in[2];
  float* out = (float*)d_out;
  dim3 grid((LL / QB) * NB);
  dim3 block(256);
  attn_fused<<<grid, block, 0, stream>>>(q, k, v, out);
}

// Round 5
// 287.538 us; speedup vs baseline: 1.8216x; 1.0025x over previous
//
#include <hip/hip_runtime.h>
#include <hip/hip_bf16.h>

#define LL 2048
#define DD 128
#define NB 32
#define KC 64
#define QB 128
#define NCH (LL / KC)
#define SCALE 0.08838834764831845f
#define C1 (SCALE * 1.4426950408889634f)

typedef short short8 __attribute__((ext_vector_type(8)));
typedef float f32x4 __attribute__((ext_vector_type(4)));
typedef float f32x16 __attribute__((ext_vector_type(16)));
typedef int int4v __attribute__((ext_vector_type(4)));
typedef unsigned int uint2v __attribute__((ext_vector_type(2)));

__device__ __forceinline__ unsigned int pkbf(float lo, float hi) {
  __hip_bfloat162 h = __float22bfloat162_rn(make_float2(lo, hi));
  union { __hip_bfloat162 h2; unsigned int u; } c;
  c.h2 = h;
  return c.u;
}
__device__ __forceinline__ float asf(unsigned int u) { return __uint_as_float(u); }

// barrier that waits only LDS ops — leaves global loads/stores in flight
__device__ __forceinline__ void barrier_lgkm() {
  asm volatile("s_waitcnt lgkmcnt(0)" ::: "memory");
  __builtin_amdgcn_s_barrier();
  asm volatile("" ::: "memory");
}

__global__ __launch_bounds__(256, 2) void attn_fused(
    const float* __restrict__ q, const float* __restrict__ k,
    const float* __restrict__ v, float* __restrict__ out) {
  // double-buffered, XOR-swizzled K [key][d] and V^T [d][key] tiles: 64 KB
  __shared__ __align__(16) unsigned short kT[2][KC * DD];
  __shared__ __align__(16) unsigned short vT[2][DD * KC];

  const int tid = threadIdx.x;
  const int w = tid >> 6, l = tid & 63;
  const int qi = l & 31;          // lane's q-row (within wave's 32)
  const int hi = l >> 5;          // half select
  const unsigned swz = (l & 7) << 3;

  // XCD-aware remap: 16 q-blocks of one batch share an XCD
  const int i0 = blockIdx.x;
  const int b  = (i0 & 7) + 8 * (i0 >> 7);
  const int qx = (i0 >> 3) & 15;
  const int qw = qx * QB + w * 32;

  const float* qb_ = q + (size_t)b * LL * DD;
  const float* kb_ = k + (size_t)b * LL * DD;
  const float* vb_ = v + (size_t)b * LL * DD;
  float* ctxW = out + ((size_t)b * LL + qw) * DD;
  float* attnRow = out + (size_t)NB * LL * DD + ((size_t)b * LL + qw + qi) * (size_t)LL;

  // staging maps
  const int krow = (tid >> 5) & 7, kc4 = tid & 31;        // K: rows krow+8j
  const int vkey0 = (tid & 15) * 4, vd0 = (tid >> 4) * 8; // V: 4 keys x 8 d

  // ---- Q fragments (B operand): lane holds Q[qw+qi][dt*16 + hi*8 + j] ----
  short8 aq[8];
  {
    const float* qrow = qb_ + (size_t)(qw + qi) * DD + hi * 8;
#pragma unroll
    for (int dt = 0; dt < 8; ++dt) {
      f32x4 x0 = *(const f32x4*)(qrow + dt * 16);
      f32x4 x1 = *(const f32x4*)(qrow + dt * 16 + 4);
      uint2v u0 = {pkbf(x0[0], x0[1]), pkbf(x0[2], x0[3])};
      uint2v u1 = {pkbf(x1[0], x1[1]), pkbf(x1[2], x1[3])};
      int4v pw = {(int)u0[0], (int)u0[1], (int)u1[0], (int)u1[1]};
      aq[dt] = __builtin_bit_cast(short8, pw);
    }
  }

  f32x4 pk[8], pv[8];

  auto loadK = [&](int kc) {
#pragma unroll
    for (int j = 0; j < 8; ++j)
      pk[j] = *(const f32x4*)(kb_ + (size_t)(kc * KC + krow + 8 * j) * DD + kc4 * 4);
  };
  auto writeK = [&](int buf) {
#pragma unroll
    for (int j = 0; j < 8; ++j) {
      uint2v y = {pkbf(pk[j][0], pk[j][1]), pkbf(pk[j][2], pk[j][3])};
      *(uint2v*)&kT[buf][(krow + 8 * j) * DD + ((kc4 * 4) ^ (krow << 3))] = y;
    }
  };
  auto loadV = [&](int kc) {
#pragma unroll
    for (int i = 0; i < 4; ++i)
#pragma unroll
      for (int h = 0; h < 2; ++h)
        pv[i * 2 + h] = *(const f32x4*)(vb_ + (size_t)(kc * KC + vkey0 + i) * DD + vd0 + h * 4);
  };
  auto writeV = [&](int buf) {
#pragma unroll
    for (int dd = 0; dd < 8; ++dd) {
      const int h = dd >> 2, c = dd & 3;
      uint2v y = {pkbf(pv[0 + h][c], pv[2 + h][c]),
                  pkbf(pv[4 + h][c], pv[6 + h][c])};
      *(uint2v*)&vT[buf][(vd0 + dd) * KC + (vkey0 ^ (dd << 3))] = y;
    }
  };

  // =================== pass 1: softmax denominators ===================
  float s = 0.f;
  loadK(0); writeK(0);
  barrier_lgkm();
  int cur = 0;
  for (int kc = 0; kc < NCH; ++kc) {
    if (kc + 1 < NCH) loadK(kc + 1);
#pragma unroll
    for (int t = 0; t < 2; ++t) {
      f32x16 acc = {0.f,0.f,0.f,0.f,0.f,0.f,0.f,0.f,0.f,0.f,0.f,0.f,0.f,0.f,0.f,0.f};
      const int arow = (t * 32 + qi) * DD;
      __builtin_amdgcn_s_setprio(1);
#pragma unroll
      for (int dt = 0; dt < 8; ++dt) {
        short8 ka = *(const short8*)&kT[cur][arow + ((dt * 16 + hi * 8) ^ swz)];
        acc = __builtin_amdgcn_mfma_f32_32x32x16_bf16(ka, aq[dt], acc, 0, 0, 0);
      }
      __builtin_amdgcn_s_setprio(0);
#pragma unroll
      for (int r = 0; r < 16; ++r) s += __builtin_amdgcn_exp2f(acc[r] * C1);
    }
    if (kc + 1 < NCH) writeK(cur ^ 1);
    barrier_lgkm();
    cur ^= 1;
  }
  s += __shfl_xor(s, 32);
  const float lrs = -__builtin_amdgcn_logf(s);   // -log2(sum)

  // =================== pass 2: attn + PV ===================
  f32x16 apv[4];
#pragma unroll
  for (int nt = 0; nt < 4; ++nt)
    apv[nt] = (f32x16){0.f,0.f,0.f,0.f,0.f,0.f,0.f,0.f,0.f,0.f,0.f,0.f,0.f,0.f,0.f,0.f};

  loadK(0); loadV(0); writeK(0); writeV(0);
  barrier_lgkm();
  cur = 0;
  for (int kc = 0; kc < NCH; ++kc) {
    if (kc + 1 < NCH) { loadK(kc + 1); loadV(kc + 1); }

#pragma unroll
    for (int t = 0; t < 2; ++t) {
      f32x16 acc = {0.f,0.f,0.f,0.f,0.f,0.f,0.f,0.f,0.f,0.f,0.f,0.f,0.f,0.f,0.f,0.f};
      const int arow = (t * 32 + qi) * DD;
      __builtin_amdgcn_s_setprio(1);
#pragma unroll
      for (int dt = 0; dt < 8; ++dt) {
        short8 ka = *(const short8*)&kT[cur][arow + ((dt * 16 + hi * 8) ^ swz)];
        acc = __builtin_amdgcn_mfma_f32_32x32x16_bf16(ka, aq[dt], acc, 0, 0, 0);
      }
      __builtin_amdgcn_s_setprio(0);

      float p[16];
#pragma unroll
      for (int r = 0; r < 16; ++r)
        p[r] = __builtin_amdgcn_exp2f(__builtin_fmaf(acc[r], C1, lrs));

#pragma unroll
      for (int kt2 = 0; kt2 < 2; ++kt2) {
        // pack to bf16 pairs; build PV A-frag words via half-swap
        const int pb0 = kt2 * 8;
        unsigned a0 = pkbf(p[pb0 + 0], p[pb0 + 1]);
        unsigned a1 = pkbf(p[pb0 + 2], p[pb0 + 3]);
        unsigned b0 = pkbf(p[pb0 + 4], p[pb0 + 5]);
        unsigned b1 = pkbf(p[pb0 + 6], p[pb0 + 7]);
        unsigned a0s = (unsigned)__shfl_xor((int)a0, 32);
        unsigned a1s = (unsigned)__shfl_xor((int)a1, 32);
        unsigned b0s = (unsigned)__shfl_xor((int)b0, 32);
        unsigned b1s = (unsigned)__shfl_xor((int)b1, 32);
        unsigned w0 = hi ? b0s : a0;
        unsigned w1 = hi ? b1s : a1;
        unsigned w2 = hi ? b0 : a0s;
        unsigned w3 = hi ? b1 : a1s;
        int4v pw = {(int)w0, (int)w1, (int)w2, (int)w3};
        short8 pa = __builtin_bit_cast(short8, pw);

        // PV first: apv[nt] += pa x V
        const int vcol = (t * 32 + kt2 * 16 + hi * 8) ^ swz;
        __builtin_amdgcn_s_setprio(1);
#pragma unroll
        for (int nt = 0; nt < 4; ++nt) {
          short8 bv = *(const short8*)&vT[cur][(nt * 32 + qi) * KC + vcol];
          apv[nt] = __builtin_amdgcn_mfma_f32_32x32x16_bf16(pa, bv, apv[nt], 0, 0, 0);
        }
        __builtin_amdgcn_s_setprio(0);

        // attn store: lane's row qi, 8 consecutive keys
        {
          f32x4 s0 = {asf(w0 << 16), asf(w0 & 0xffff0000u),
                      asf(w1 << 16), asf(w1 & 0xffff0000u)};
          f32x4 s1 = {asf(w2 << 16), asf(w2 & 0xffff0000u),
                      asf(w3 << 16), asf(w3 & 0xffff0000u)};
          float* dst = attnRow + kc * KC + t * 32 + kt2 * 16 + hi * 8;
          *(f32x4*)dst = s0;
          *(f32x4*)(dst + 4) = s1;
        }
      }
    }

    if (kc + 1 < NCH) { writeK(cur ^ 1); writeV(cur ^ 1); }
    barrier_lgkm();
    cur ^= 1;
  }

  // ---- context store: D rows = (r&3)+8*(r>>2)+4*hi, col = nt*32+qi ----
#pragma unroll
  for (int nt = 0; nt < 4; ++nt)
#pragma unroll
    for (int r = 0; r < 16; ++r) {
      const int row = (r & 3) + 8 * (r >> 2) + 4 * hi;
      ctxW[(size_t)row * DD + nt * 32 + qi] = apv[nt][r];
    }
}

extern "C" void kernel_launch(void* const* d_in, const int* in_sizes, int n_in,
                              void* d_out, int out_size, void* d_ws, size_t ws_size,
                              hipStream_t stream) {
  const float* q = (const float*)d_in[0];
  const float* k = (const float*)d_in[1];
  const float* v = (const float*)d_in[2];
  float* out = (float*)d_out;
  dim3 grid((LL / QB) * NB);
  dim3 block(256);
  attn_fused<<<grid, block, 0, stream>>>(q, k, v, out);
}